// Round 1
// baseline (413.490 us; speedup 1.0000x reference)
//
#include <hip/hip_runtime.h>
#include <hip/hip_bf16.h>

// out[r,2j]   = cos(q[2j]) * cos(pi * x[r,2j])
// out[r,2j+1] = out[r,2j]  * cos(q[2j+1] + pi * x[r,2j+1])
// Row = 16 floats = 4 float4s; float4 #c within a row covers pairs j=2c, 2c+1,
// and q viewed as float4[4] gives (qe0, qo0, qe1, qo1) at index c directly.

__global__ __launch_bounds__(256) void qconv_kernel(
    const float* __restrict__ x, const float* __restrict__ q,
    float* __restrict__ out, int n4) {
    int idx = blockIdx.x * blockDim.x + threadIdx.x;
    if (idx >= n4) return;

    const float PI = 3.14159265358979323846f;

    // which float4 within the 16-float row
    int c = idx & 3;
    float4 q4 = reinterpret_cast<const float4*>(q)[c];  // (qe0, qo0, qe1, qo1)

    float4 v = reinterpret_cast<const float4*>(x)[idx]; // (xe0, xo0, xe1, xo1)

    float cqe0 = __cosf(q4.x);
    float cqe1 = __cosf(q4.z);

    float ze0 = cqe0 * __cosf(PI * v.x);
    float zo0 = ze0  * __cosf(q4.y + PI * v.y);
    float ze1 = cqe1 * __cosf(PI * v.z);
    float zo1 = ze1  * __cosf(q4.w + PI * v.w);

    float4 r;
    r.x = ze0; r.y = zo0; r.z = ze1; r.w = zo1;
    reinterpret_cast<float4*>(out)[idx] = r;
}

extern "C" void kernel_launch(void* const* d_in, const int* in_sizes, int n_in,
                              void* d_out, int out_size, void* d_ws, size_t ws_size,
                              hipStream_t stream) {
    const float* x = (const float*)d_in[0];
    const float* q = (const float*)d_in[1];
    float* out = (float*)d_out;

    int n = in_sizes[0];       // B * 16 = 67108864
    int n4 = n / 4;            // 16777216 float4s

    const int block = 256;
    int grid = (n4 + block - 1) / block;
    qconv_kernel<<<grid, block, 0, stream>>>(x, q, out, n4);
}